// Round 1
// baseline (408.931 us; speedup 1.0000x reference)
//
#include <hip/hip_runtime.h>
#include <hip/hip_bf16.h>
#include <math.h>

// Problem constants
#define BATCH 1024
#define FEAT  2048
#define NCLS  11003
#define NPAD  11008      // 86 * 128
#define NT1   86         // N tiles for gemm1
#define NPART (NT1 * 2)  // partials per row (2 waves in N per tile)
#define M1    2048       // stacked [v; t]
#define C_SCALE  28.0f
#define C_ALPHA  0.6f
#define C_BETA   0.4f
#define C_SPOS   10.0f
#define C_SNEG   40.0f

typedef __bf16 bf16_t;
typedef __bf16 bf16x8 __attribute__((ext_vector_type(8)));
typedef float  floatx4 __attribute__((ext_vector_type(4)));

// ---- workspace layout (bytes, all 256-aligned) ----
#define O_ALIGN  ((size_t)0)                        // 1 f32 accumulator
#define O_COLSQ  ((size_t)256)                      // NPAD f32
#define O_XN     ((size_t)44288)                    // 2048*2048 bf16 (normalized [v;t])
#define O_WT     ((size_t)8432896)                  // NPAD*2048 bf16 (W^T, unscaled)
#define O_PMAX   ((size_t)53521664)                 // 2048*NPART f32
#define O_PSUM   ((size_t)54930688)                 // 2048*NPART f32
#define O_LL     ((size_t)56339712)                 // 2048 f32 label logits
#define O_CE     ((size_t)56347904)                 // 2048 f32 per-row CE terms

__device__ inline float softplusf(float x) {
    return (x > 20.f) ? x : log1pf(expf(x));
}

// ---------------- row-normalize [v; t] -> bf16 ----------------
__global__ __launch_bounds__(256) void k_rownorm(const float* __restrict__ vis,
                                                 const float* __restrict__ txt,
                                                 __hip_bfloat16* __restrict__ Xn) {
    int r = blockIdx.x;
    const float* src = (r < BATCH) ? (vis + (size_t)r * FEAT)
                                   : (txt + (size_t)(r - BATCH) * FEAT);
    int t = threadIdx.x;
    float4 x0 = ((const float4*)src)[t];
    float4 x1 = ((const float4*)src)[t + 256];
    float ss = x0.x*x0.x + x0.y*x0.y + x0.z*x0.z + x0.w*x0.w
             + x1.x*x1.x + x1.y*x1.y + x1.z*x1.z + x1.w*x1.w;
    __shared__ float sb[256];
    sb[t] = ss; __syncthreads();
    for (int s = 128; s > 0; s >>= 1) { if (t < s) sb[t] += sb[t + s]; __syncthreads(); }
    float rn = rsqrtf(sb[0]);
    __hip_bfloat16* dst = Xn + (size_t)r * FEAT;
    dst[4*t + 0]        = __float2bfloat16(x0.x * rn);
    dst[4*t + 1]        = __float2bfloat16(x0.y * rn);
    dst[4*t + 2]        = __float2bfloat16(x0.z * rn);
    dst[4*t + 3]        = __float2bfloat16(x0.w * rn);
    dst[4*(t+256) + 0]  = __float2bfloat16(x1.x * rn);
    dst[4*(t+256) + 1]  = __float2bfloat16(x1.y * rn);
    dst[4*(t+256) + 2]  = __float2bfloat16(x1.z * rn);
    dst[4*(t+256) + 3]  = __float2bfloat16(x1.w * rn);
}

// ---------------- W: column sumsq + bf16 transpose ----------------
// grid (172 c-tiles, 32 f-tiles), 256 threads; 64x64 tile through LDS
__global__ __launch_bounds__(256) void k_wprep(const float* __restrict__ W,
                                               __hip_bfloat16* __restrict__ WT,
                                               float* __restrict__ colsq) {
    __shared__ __hip_bfloat16 tile[64][65];
    int c0 = blockIdx.x * 64, f0 = blockIdx.y * 64;
    int t = threadIdx.x, tr = t >> 6, tc = t & 63;
    int c = c0 + tc;
    float part = 0.f;
    for (int rr = tr; rr < 64; rr += 4) {
        float w = (c < NCLS) ? W[(size_t)(f0 + rr) * NCLS + c] : 0.f;
        part += w * w;
        tile[rr][tc] = __float2bfloat16(w);
    }
    if (c < NCLS) atomicAdd(&colsq[c], part);
    __syncthreads();
    for (int cc = tr; cc < 64; cc += 4) {
        WT[(size_t)(c0 + cc) * FEAT + f0 + tc] = tile[tc][cc];
    }
}

// ---------------- shared GEMM core: acc[m][n] = sum_k A[m][k]*B[n][k] ----------------
// A: [*][FEAT] bf16 k-contig, B: [*][FEAT] bf16 k-contig. 128x128 tile, 4 waves 2x2,
// each wave 64x64 via 4x4 grid of 16x16x32 MFMA. Register-staged LDS, 64 K-iters.
__device__ inline void gemm_core(const __hip_bfloat16* __restrict__ A,
                                 const __hip_bfloat16* __restrict__ B,
                                 int m0, int n0,
                                 bf16_t* As, bf16_t* Bs,
                                 floatx4 (&acc)[4][4]) {
    const int t = threadIdx.x;
    const int rowA = t >> 1, koff = (t & 1) * 16;
    const ushort* Ag = (const ushort*)(A + (size_t)(m0 + rowA) * FEAT + koff);
    const ushort* Bg = (const ushort*)(B + (size_t)(n0 + rowA) * FEAT + koff);
    uint4* AsW = (uint4*)(As + t * 16);
    uint4* BsW = (uint4*)(Bs + t * 16);
    const int wave = t >> 6, lane = t & 63;
    const int wm = wave >> 1, wn = wave & 1;
    const int quad = lane >> 4, l16 = lane & 15;
    const bf16x8* Ard[4]; const bf16x8* Brd[4];
    #pragma unroll
    for (int i = 0; i < 4; ++i) {
        Ard[i] = (const bf16x8*)(As + (wm*64 + i*16 + l16) * 32 + quad * 8);
        Brd[i] = (const bf16x8*)(Bs + (wn*64 + i*16 + l16) * 32 + quad * 8);
    }
    for (int kt = 0; kt < FEAT / 32; ++kt) {
        uint4 a0 = *(const uint4*)(Ag);
        uint4 a1 = *(const uint4*)(Ag + 8);
        uint4 b0 = *(const uint4*)(Bg);
        uint4 b1 = *(const uint4*)(Bg + 8);
        Ag += 32; Bg += 32;
        __syncthreads();                 // previous tile's compute done
        AsW[0] = a0; AsW[1] = a1;
        BsW[0] = b0; BsW[1] = b1;
        __syncthreads();                 // tile staged
        bf16x8 af[4], bfr[4];
        #pragma unroll
        for (int i = 0; i < 4; ++i) { af[i] = *Ard[i]; bfr[i] = *Brd[i]; }
        #pragma unroll
        for (int i = 0; i < 4; ++i)
            #pragma unroll
            for (int j = 0; j < 4; ++j)
                acc[i][j] = __builtin_amdgcn_mfma_f32_16x16x32_bf16(af[i], bfr[j], acc[i][j], 0, 0, 0);
    }
}

// ---------------- GEMM1: logits -> per-tile (rowmax, rowsumexp) partials ----------------
__global__ __launch_bounds__(256) void k_gemm_lse(const __hip_bfloat16* __restrict__ Xn,
                                                  const __hip_bfloat16* __restrict__ WT,
                                                  const float* __restrict__ colsq,
                                                  float* __restrict__ pmax,
                                                  float* __restrict__ psum) {
    __shared__ bf16_t As[128 * 32], Bs[128 * 32];
    floatx4 acc[4][4] = {};
    int n0 = blockIdx.x * 128, m0 = blockIdx.y * 128;
    gemm_core(Xn, WT, m0, n0, As, Bs, acc);

    const int t = threadIdx.x, wave = t >> 6, lane = t & 63;
    const int wm = wave >> 1, wn = wave & 1, quad = lane >> 4, l16 = lane & 15;
    float rcol[4]; bool val[4];
    #pragma unroll
    for (int j = 0; j < 4; ++j) {
        int nj = n0 + wn*64 + j*16 + l16;
        val[j] = (nj < NCLS);
        rcol[j] = val[j] ? rsqrtf(colsq[nj]) : 0.f;
    }
    const int pidx = blockIdx.x * 2 + wn;
    #pragma unroll
    for (int i = 0; i < 4; ++i) {
        #pragma unroll
        for (int reg = 0; reg < 4; ++reg) {
            float v[4]; float mx = -1e30f;
            #pragma unroll
            for (int j = 0; j < 4; ++j) {
                v[j] = val[j] ? (C_SCALE * acc[i][j][reg] * rcol[j]) : -1e30f;
                mx = fmaxf(mx, v[j]);
            }
            for (int off = 1; off < 16; off <<= 1) mx = fmaxf(mx, __shfl_xor(mx, off));
            float s = 0.f;
            #pragma unroll
            for (int j = 0; j < 4; ++j) if (val[j]) s += expf(v[j] - mx);
            for (int off = 1; off < 16; off <<= 1) s += __shfl_xor(s, off);
            if (l16 == 0) {
                int m = m0 + wm*64 + i*16 + quad*4 + reg;
                pmax[(size_t)m * NPART + pidx] = mx;
                psum[(size_t)m * NPART + pidx] = s;
            }
        }
    }
}

// ---------------- GEMM2: sim = v . t^T -> masked softplus sum ----------------
__global__ __launch_bounds__(256) void k_gemm_sim(const __hip_bfloat16* __restrict__ Xn,
                                                  const int* __restrict__ labels,
                                                  float* __restrict__ align_sum) {
    __shared__ bf16_t As[128 * 32], Bs[128 * 32];
    floatx4 acc[4][4] = {};
    int n0 = blockIdx.x * 128, m0 = blockIdx.y * 128;
    gemm_core(Xn, Xn + (size_t)BATCH * FEAT, m0, n0, As, Bs, acc);

    const int t = threadIdx.x, wave = t >> 6, lane = t & 63;
    const int wm = wave >> 1, wn = wave & 1, quad = lane >> 4, l16 = lane & 15;
    int ln[4];
    #pragma unroll
    for (int j = 0; j < 4; ++j) ln[j] = labels[n0 + wn*64 + j*16 + l16];
    float tot = 0.f;
    #pragma unroll
    for (int i = 0; i < 4; ++i) {
        #pragma unroll
        for (int reg = 0; reg < 4; ++reg) {
            int m = m0 + wm*64 + i*16 + quad*4 + reg;
            int lm = labels[m];
            #pragma unroll
            for (int j = 0; j < 4; ++j) {
                float s = acc[i][j][reg];
                float arg = (lm == ln[j]) ? (-C_SPOS * (s - C_ALPHA))
                                          : ( C_SNEG * (s - C_BETA));
                tot += softplusf(arg);
            }
        }
    }
    for (int off = 1; off < 64; off <<= 1) tot += __shfl_xor(tot, off);
    if (lane == 0) atomicAdd(align_sum, tot);
}

// ---------------- label logits (consistent bf16 inputs) ----------------
__global__ __launch_bounds__(256) void k_ll(const __hip_bfloat16* __restrict__ Xn,
                                            const __hip_bfloat16* __restrict__ WT,
                                            const int* __restrict__ labels,
                                            const float* __restrict__ colsq,
                                            float* __restrict__ ll) {
    int r = blockIdx.x * 4 + (threadIdx.x >> 6);
    int lane = threadIdx.x & 63;
    int lab = labels[r & (BATCH - 1)];
    const __hip_bfloat16* x = Xn + (size_t)r * FEAT;
    const __hip_bfloat16* w = WT + (size_t)lab * FEAT;
    float s = 0.f;
    for (int k = lane; k < FEAT; k += 64)
        s += __bfloat162float(x[k]) * __bfloat162float(w[k]);
    for (int off = 1; off < 64; off <<= 1) s += __shfl_xor(s, off);
    if (lane == 0) ll[r] = C_SCALE * rsqrtf(colsq[lab]) * s;
}

// ---------------- merge partials -> per-row CE term ----------------
__global__ __launch_bounds__(256) void k_merge(const float* __restrict__ pmax,
                                               const float* __restrict__ psum,
                                               const float* __restrict__ ll,
                                               float* __restrict__ ce) {
    int r = blockIdx.x, t = threadIdx.x;
    float mx = -1e30f, sm = 0.f;
    if (t < NPART) { mx = pmax[(size_t)r * NPART + t]; sm = psum[(size_t)r * NPART + t]; }
    __shared__ float sb[256];
    sb[t] = mx; __syncthreads();
    for (int s = 128; s > 0; s >>= 1) { if (t < s) sb[t] = fmaxf(sb[t], sb[t+s]); __syncthreads(); }
    float M = sb[0]; __syncthreads();
    float c = sm * expf(mx - M);   // masked entries: 0 * exp(-inf) = 0
    sb[t] = c; __syncthreads();
    for (int s = 128; s > 0; s >>= 1) { if (t < s) sb[t] += sb[t+s]; __syncthreads(); }
    if (t == 0) ce[r] = M + logf(sb[0]) - ll[r];
}

// ---------------- final: two scalars ----------------
__global__ __launch_bounds__(256) void k_final(const float* __restrict__ ce,
                                               const float* __restrict__ align_sum,
                                               float* __restrict__ out) {
    int t = threadIdx.x;
    float s = 0.f;
    for (int i = t; i < M1; i += 256) s += ce[i];
    __shared__ float sb[256];
    sb[t] = s; __syncthreads();
    for (int k = 128; k > 0; k >>= 1) { if (t < k) sb[t] += sb[t+k]; __syncthreads(); }
    if (t == 0) {
        out[0] = sb[0] / (float)BATCH;
        out[1] = align_sum[0] * 2.f / (float)BATCH;
    }
}

extern "C" void kernel_launch(void* const* d_in, const int* in_sizes, int n_in,
                              void* d_out, int out_size, void* d_ws, size_t ws_size,
                              hipStream_t stream) {
    const float* vis    = (const float*)d_in[0];
    const float* txt    = (const float*)d_in[1];
    const int*   labels = (const int*)  d_in[2];
    const float* W      = (const float*)d_in[3];
    float* out = (float*)d_out;
    char*  ws  = (char*)d_ws;

    float* align_sum = (float*)(ws + O_ALIGN);
    float* colsq     = (float*)(ws + O_COLSQ);
    __hip_bfloat16* Xn = (__hip_bfloat16*)(ws + O_XN);
    __hip_bfloat16* WT = (__hip_bfloat16*)(ws + O_WT);
    float* pmax = (float*)(ws + O_PMAX);
    float* psum = (float*)(ws + O_PSUM);
    float* ll   = (float*)(ws + O_LL);
    float* ce   = (float*)(ws + O_CE);

    // zero align_sum + colsq (everything before O_XN)
    hipMemsetAsync(ws, 0, O_XN, stream);

    k_rownorm<<<dim3(M1), 256, 0, stream>>>(vis, txt, Xn);
    k_wprep  <<<dim3(172, 32), 256, 0, stream>>>(W, WT, colsq);
    k_gemm_lse<<<dim3(NT1, M1 / 128), 256, 0, stream>>>(Xn, WT, colsq, pmax, psum);
    k_gemm_sim<<<dim3(BATCH / 128, BATCH / 128), 256, 0, stream>>>(Xn, labels, align_sum);
    k_ll     <<<dim3(M1 / 4), 256, 0, stream>>>(Xn, WT, labels, colsq, ll);
    k_merge  <<<dim3(M1), 256, 0, stream>>>(pmax, psum, ll, ce);
    k_final  <<<dim3(1), 256, 0, stream>>>(ce, align_sum, out);
}

// Round 2
// 378.258 us; speedup vs baseline: 1.0811x; 1.0811x over previous
//
#include <hip/hip_runtime.h>
#include <hip/hip_bf16.h>
#include <math.h>

// Problem constants
#define BATCH 1024
#define FEAT  2048
#define NCLS  11003
#define NPAD  11008      // 86 * 128
#define NT1   86         // N tiles for gemm1
#define NPART (NT1 * 2)  // partials per row (2 waves in N per tile)
#define M1    2048       // stacked [v; t]
#define C_SCALE  28.0f
#define C_ALPHA  0.6f
#define C_BETA   0.4f
#define C_SPOS   10.0f
#define C_SNEG   40.0f

typedef __bf16 bf16_t;
typedef __bf16 bf16x8 __attribute__((ext_vector_type(8)));
typedef float  floatx4 __attribute__((ext_vector_type(4)));

// ---- workspace layout (bytes, all 256-aligned) ----
#define O_ALIGN  ((size_t)0)                        // 1 f32 accumulator
#define O_COLSQ  ((size_t)256)                      // NPAD f32
#define O_XN     ((size_t)44288)                    // 2048*2048 bf16 (normalized [v;t])
#define O_WT     ((size_t)8432896)                  // NPAD*2048 bf16 (W^T, unscaled)
#define O_PMAX   ((size_t)53521664)                 // 2048*NPART f32
#define O_PSUM   ((size_t)54930688)                 // 2048*NPART f32
#define O_LL     ((size_t)56339712)                 // 2048 f32 label logits
#define O_CE     ((size_t)56347904)                 // 2048 f32 per-row CE terms

__device__ inline float softplusf(float x) {
    return (x > 20.f) ? x : log1pf(expf(x));
}

// async 16B global -> LDS (wave-uniform base + lane*16; our layout is lane-linear)
__device__ inline void gll16(const void* g, void* l) {
    __builtin_amdgcn_global_load_lds(
        (const __attribute__((address_space(1))) unsigned int*)g,
        (__attribute__((address_space(3))) unsigned int*)l, 16, 0, 0);
}

// ---------------- row-normalize [v; t] -> bf16 ----------------
__global__ __launch_bounds__(256) void k_rownorm(const float* __restrict__ vis,
                                                 const float* __restrict__ txt,
                                                 __hip_bfloat16* __restrict__ Xn) {
    int r = blockIdx.x;
    const float* src = (r < BATCH) ? (vis + (size_t)r * FEAT)
                                   : (txt + (size_t)(r - BATCH) * FEAT);
    int t = threadIdx.x;
    float4 x0 = ((const float4*)src)[t];
    float4 x1 = ((const float4*)src)[t + 256];
    float ss = x0.x*x0.x + x0.y*x0.y + x0.z*x0.z + x0.w*x0.w
             + x1.x*x1.x + x1.y*x1.y + x1.z*x1.z + x1.w*x1.w;
    __shared__ float sb[256];
    sb[t] = ss; __syncthreads();
    for (int s = 128; s > 0; s >>= 1) { if (t < s) sb[t] += sb[t + s]; __syncthreads(); }
    float rn = rsqrtf(sb[0]);
    __hip_bfloat16* dst = Xn + (size_t)r * FEAT;
    dst[4*t + 0]        = __float2bfloat16(x0.x * rn);
    dst[4*t + 1]        = __float2bfloat16(x0.y * rn);
    dst[4*t + 2]        = __float2bfloat16(x0.z * rn);
    dst[4*t + 3]        = __float2bfloat16(x0.w * rn);
    dst[4*(t+256) + 0]  = __float2bfloat16(x1.x * rn);
    dst[4*(t+256) + 1]  = __float2bfloat16(x1.y * rn);
    dst[4*(t+256) + 2]  = __float2bfloat16(x1.z * rn);
    dst[4*(t+256) + 3]  = __float2bfloat16(x1.w * rn);
}

// ---------------- W: column sumsq + bf16 transpose ----------------
// grid (172 c-tiles, 32 f-tiles), 256 threads; 64x64 tile through LDS
__global__ __launch_bounds__(256) void k_wprep(const float* __restrict__ W,
                                               __hip_bfloat16* __restrict__ WT,
                                               float* __restrict__ colsq) {
    __shared__ __hip_bfloat16 tile[64][65];
    __shared__ float cp[4][64];
    int c0 = blockIdx.x * 64, f0 = blockIdx.y * 64;
    int t = threadIdx.x, tr = t >> 6, tc = t & 63;
    int c = c0 + tc;
    float part = 0.f;
    #pragma unroll
    for (int rr = tr; rr < 64; rr += 4) {
        float w = (c < NCLS) ? W[(size_t)(f0 + rr) * NCLS + c] : 0.f;
        part += w * w;
        tile[rr][tc] = __float2bfloat16(w);
    }
    cp[tr][tc] = part;
    __syncthreads();
    if (tr == 0 && c < NCLS)
        atomicAdd(&colsq[c], cp[0][tc] + cp[1][tc] + cp[2][tc] + cp[3][tc]);
    // vectorized WT write: 16B per lane along the feature dim
    #pragma unroll
    for (int idx = t; idx < 512; idx += 256) {
        int cc = idx >> 3, ff = (idx & 7) * 8;
        bf16_t tmp[8];
        #pragma unroll
        for (int u = 0; u < 8; ++u) tmp[u] = *(bf16_t*)&tile[ff + u][cc];
        *(uint4*)&WT[(size_t)(c0 + cc) * FEAT + f0 + ff] = *(uint4*)tmp;
    }
}

// ---------------- shared GEMM core: acc[m][n] = sum_k A[m][k]*B[n][k] ----------------
// A: [*][FEAT] bf16 k-contig, B: [*][FEAT] bf16 k-contig. 128x128 tile, 4 waves 2x2,
// each wave 64x64 via 4x4 grid of 16x16x32 MFMA. global_load_lds width=16 staging.
// LDS tile layout: chunk c (16B) at byte c*16 = row (c>>2)*64B + (c&3)*16B.
__device__ inline void gemm_core(const __hip_bfloat16* __restrict__ A,
                                 const __hip_bfloat16* __restrict__ B,
                                 int m0, int n0,
                                 bf16_t* As, bf16_t* Bs,
                                 floatx4 (&acc)[4][4]) {
    const int t = threadIdx.x;
    // staging chunk indices: inst0 -> c = t (rows 0..63), inst1 -> c = 256+t (rows 64..127)
    const int r0 = t >> 2,        kc0 = t & 3;
    const int r1 = (256 + t) >> 2, kc1 = t & 3;
    const ushort* Ag0 = (const ushort*)(A + (size_t)(m0 + r0) * FEAT + kc0 * 8);
    const ushort* Ag1 = (const ushort*)(A + (size_t)(m0 + r1) * FEAT + kc1 * 8);
    const ushort* Bg0 = (const ushort*)(B + (size_t)(n0 + r0) * FEAT + kc0 * 8);
    const ushort* Bg1 = (const ushort*)(B + (size_t)(n0 + r1) * FEAT + kc1 * 8);
    bf16_t* lA0 = As + t * 8;          // bytes: t*16
    bf16_t* lA1 = As + 2048 + t * 8;   // bytes: 4096 + t*16
    bf16_t* lB0 = Bs + t * 8;
    bf16_t* lB1 = Bs + 2048 + t * 8;

    const int wave = t >> 6, lane = t & 63;
    const int wm = wave >> 1, wn = wave & 1;
    const int quad = lane >> 4, l16 = lane & 15;
    const bf16x8* Ard[4]; const bf16x8* Brd[4];
    #pragma unroll
    for (int i = 0; i < 4; ++i) {
        Ard[i] = (const bf16x8*)(As + (wm*64 + i*16 + l16) * 32 + quad * 8);
        Brd[i] = (const bf16x8*)(Bs + (wn*64 + i*16 + l16) * 32 + quad * 8);
    }
    for (int kt = 0; kt < FEAT / 32; ++kt) {
        __syncthreads();                 // previous tile's LDS reads done
        gll16(Ag0, lA0);
        gll16(Ag1, lA1);
        gll16(Bg0, lB0);
        gll16(Bg1, lB1);
        Ag0 += 32; Ag1 += 32; Bg0 += 32; Bg1 += 32;
        __syncthreads();                 // loads landed (vmcnt drained at barrier)
        bf16x8 af[4], bfr[4];
        #pragma unroll
        for (int i = 0; i < 4; ++i) { af[i] = *Ard[i]; bfr[i] = *Brd[i]; }
        #pragma unroll
        for (int i = 0; i < 4; ++i)
            #pragma unroll
            for (int j = 0; j < 4; ++j)
                acc[i][j] = __builtin_amdgcn_mfma_f32_16x16x32_bf16(af[i], bfr[j], acc[i][j], 0, 0, 0);
    }
}

// ---------------- GEMM1: logits -> per-tile (rowmax, rowsumexp) partials ----------------
__global__ __launch_bounds__(256) void k_gemm_lse(const __hip_bfloat16* __restrict__ Xn,
                                                  const __hip_bfloat16* __restrict__ WT,
                                                  const float* __restrict__ colsq,
                                                  float* __restrict__ pmax,
                                                  float* __restrict__ psum) {
    __shared__ bf16_t As[128 * 32], Bs[128 * 32];
    floatx4 acc[4][4] = {};
    int n0 = blockIdx.x * 128, m0 = blockIdx.y * 128;
    gemm_core(Xn, WT, m0, n0, As, Bs, acc);

    const int t = threadIdx.x, wave = t >> 6, lane = t & 63;
    const int wm = wave >> 1, wn = wave & 1, quad = lane >> 4, l16 = lane & 15;
    float rcol[4]; bool val[4];
    #pragma unroll
    for (int j = 0; j < 4; ++j) {
        int nj = n0 + wn*64 + j*16 + l16;
        val[j] = (nj < NCLS);
        rcol[j] = val[j] ? rsqrtf(colsq[nj]) : 0.f;
    }
    const int pidx = blockIdx.x * 2 + wn;
    #pragma unroll
    for (int i = 0; i < 4; ++i) {
        #pragma unroll
        for (int reg = 0; reg < 4; ++reg) {
            float v[4]; float mx = -1e30f;
            #pragma unroll
            for (int j = 0; j < 4; ++j) {
                v[j] = val[j] ? (C_SCALE * acc[i][j][reg] * rcol[j]) : -1e30f;
                mx = fmaxf(mx, v[j]);
            }
            for (int off = 1; off < 16; off <<= 1) mx = fmaxf(mx, __shfl_xor(mx, off));
            float s = 0.f;
            #pragma unroll
            for (int j = 0; j < 4; ++j) if (val[j]) s += expf(v[j] - mx);
            for (int off = 1; off < 16; off <<= 1) s += __shfl_xor(s, off);
            if (l16 == 0) {
                int m = m0 + wm*64 + i*16 + quad*4 + reg;
                pmax[(size_t)m * NPART + pidx] = mx;
                psum[(size_t)m * NPART + pidx] = s;
            }
        }
    }
}

// ---------------- GEMM2: sim = v . t^T -> masked softplus sum ----------------
__global__ __launch_bounds__(256) void k_gemm_sim(const __hip_bfloat16* __restrict__ Xn,
                                                  const int* __restrict__ labels,
                                                  float* __restrict__ align_sum) {
    __shared__ bf16_t As[128 * 32], Bs[128 * 32];
    floatx4 acc[4][4] = {};
    int n0 = blockIdx.x * 128, m0 = blockIdx.y * 128;
    gemm_core(Xn, Xn + (size_t)BATCH * FEAT, m0, n0, As, Bs, acc);

    const int t = threadIdx.x, wave = t >> 6, lane = t & 63;
    const int wm = wave >> 1, wn = wave & 1, quad = lane >> 4, l16 = lane & 15;
    int ln[4];
    #pragma unroll
    for (int j = 0; j < 4; ++j) ln[j] = labels[n0 + wn*64 + j*16 + l16];
    float tot = 0.f;
    #pragma unroll
    for (int i = 0; i < 4; ++i) {
        #pragma unroll
        for (int reg = 0; reg < 4; ++reg) {
            int m = m0 + wm*64 + i*16 + quad*4 + reg;
            int lm = labels[m];
            #pragma unroll
            for (int j = 0; j < 4; ++j) {
                float s = acc[i][j][reg];
                float arg = (lm == ln[j]) ? (-C_SPOS * (s - C_ALPHA))
                                          : ( C_SNEG * (s - C_BETA));
                tot += softplusf(arg);
            }
        }
    }
    for (int off = 1; off < 64; off <<= 1) tot += __shfl_xor(tot, off);
    if (lane == 0) atomicAdd(align_sum, tot);
}

// ---------------- label logits (consistent bf16 inputs) ----------------
__global__ __launch_bounds__(256) void k_ll(const __hip_bfloat16* __restrict__ Xn,
                                            const __hip_bfloat16* __restrict__ WT,
                                            const int* __restrict__ labels,
                                            const float* __restrict__ colsq,
                                            float* __restrict__ ll) {
    int r = blockIdx.x * 4 + (threadIdx.x >> 6);
    int lane = threadIdx.x & 63;
    int lab = labels[r & (BATCH - 1)];
    const __hip_bfloat16* x = Xn + (size_t)r * FEAT;
    const __hip_bfloat16* w = WT + (size_t)lab * FEAT;
    float s = 0.f;
    for (int k = lane; k < FEAT; k += 64)
        s += __bfloat162float(x[k]) * __bfloat162float(w[k]);
    for (int off = 1; off < 64; off <<= 1) s += __shfl_xor(s, off);
    if (lane == 0) ll[r] = C_SCALE * rsqrtf(colsq[lab]) * s;
}

// ---------------- merge partials -> per-row CE term ----------------
__global__ __launch_bounds__(256) void k_merge(const float* __restrict__ pmax,
                                               const float* __restrict__ psum,
                                               const float* __restrict__ ll,
                                               float* __restrict__ ce) {
    int r = blockIdx.x, t = threadIdx.x;
    float mx = -1e30f, sm = 0.f;
    if (t < NPART) { mx = pmax[(size_t)r * NPART + t]; sm = psum[(size_t)r * NPART + t]; }
    __shared__ float sb[256];
    sb[t] = mx; __syncthreads();
    for (int s = 128; s > 0; s >>= 1) { if (t < s) sb[t] = fmaxf(sb[t], sb[t+s]); __syncthreads(); }
    float M = sb[0]; __syncthreads();
    float c = sm * expf(mx - M);   // masked entries: 0 * exp(-inf) = 0
    sb[t] = c; __syncthreads();
    for (int s = 128; s > 0; s >>= 1) { if (t < s) sb[t] += sb[t+s]; __syncthreads(); }
    if (t == 0) ce[r] = M + logf(sb[0]) - ll[r];
}

// ---------------- final: two scalars ----------------
__global__ __launch_bounds__(256) void k_final(const float* __restrict__ ce,
                                               const float* __restrict__ align_sum,
                                               float* __restrict__ out) {
    int t = threadIdx.x;
    float s = 0.f;
    for (int i = t; i < M1; i += 256) s += ce[i];
    __shared__ float sb[256];
    sb[t] = s; __syncthreads();
    for (int k = 128; k > 0; k >>= 1) { if (t < k) sb[t] += sb[t+k]; __syncthreads(); }
    if (t == 0) {
        out[0] = sb[0] / (float)BATCH;
        out[1] = align_sum[0] * 2.f / (float)BATCH;
    }
}

extern "C" void kernel_launch(void* const* d_in, const int* in_sizes, int n_in,
                              void* d_out, int out_size, void* d_ws, size_t ws_size,
                              hipStream_t stream) {
    const float* vis    = (const float*)d_in[0];
    const float* txt    = (const float*)d_in[1];
    const int*   labels = (const int*)  d_in[2];
    const float* W      = (const float*)d_in[3];
    float* out = (float*)d_out;
    char*  ws  = (char*)d_ws;

    float* align_sum = (float*)(ws + O_ALIGN);
    float* colsq     = (float*)(ws + O_COLSQ);
    __hip_bfloat16* Xn = (__hip_bfloat16*)(ws + O_XN);
    __hip_bfloat16* WT = (__hip_bfloat16*)(ws + O_WT);
    float* pmax = (float*)(ws + O_PMAX);
    float* psum = (float*)(ws + O_PSUM);
    float* ll   = (float*)(ws + O_LL);
    float* ce   = (float*)(ws + O_CE);

    // zero align_sum + colsq (everything before O_XN)
    hipMemsetAsync(ws, 0, O_XN, stream);

    k_rownorm<<<dim3(M1), 256, 0, stream>>>(vis, txt, Xn);
    k_wprep  <<<dim3(172, 32), 256, 0, stream>>>(W, WT, colsq);
    k_gemm_lse<<<dim3(NT1, M1 / 128), 256, 0, stream>>>(Xn, WT, colsq, pmax, psum);
    k_gemm_sim<<<dim3(BATCH / 128, BATCH / 128), 256, 0, stream>>>(Xn, labels, align_sum);
    k_ll     <<<dim3(M1 / 4), 256, 0, stream>>>(Xn, WT, labels, colsq, ll);
    k_merge  <<<dim3(M1), 256, 0, stream>>>(pmax, psum, ll, ce);
    k_final  <<<dim3(1), 256, 0, stream>>>(ce, align_sum, out);
}

// Round 3
// 356.878 us; speedup vs baseline: 1.1459x; 1.0599x over previous
//
#include <hip/hip_runtime.h>
#include <hip/hip_bf16.h>
#include <math.h>

// Problem constants
#define BATCH 1024
#define FEAT  2048
#define NCLS  11003
#define NPAD  11008      // 86 * 128
#define NT1   86         // N tiles for gemm1
#define NPART (NT1 * 2)  // partials per row (2 waves in N per tile)
#define M1    2048       // stacked [v; t]
#define C_SCALE  28.0f
#define C_ALPHA  0.6f
#define C_BETA   0.4f
#define C_SPOS   10.0f
#define C_SNEG   40.0f

typedef __bf16 bf16_t;
typedef __bf16 bf16x8 __attribute__((ext_vector_type(8)));
typedef float  floatx4 __attribute__((ext_vector_type(4)));

// ---- workspace layout (bytes) ----
#define O_ALIGN  ((size_t)0)                        // f32 align_sum
#define O_INST   ((size_t)64)                       // f32 instance-CE sum
#define O_COLSQ  ((size_t)256)                      // NPAD f32
#define O_XN     ((size_t)44288)                    // 2048*2048 bf16 (normalized [v;t])
#define O_WT     ((size_t)8432896)                  // NPAD*2048 bf16 (W^T, unscaled)
#define O_PMAX   ((size_t)53521664)                 // 2048*NPART f32
#define O_PSUM   ((size_t)54930688)                 // 2048*NPART f32
#define O_LL     ((size_t)56339712)                 // 2048 f32 label logits
// zeroed prefix: [0, O_XN)

#define PREP_WBLOCKS (172 * 32)   // 5504 wprep blocks (first: longest work)
#define PREP_TOTAL   (PREP_WBLOCKS + M1)

__device__ inline float softplusf(float x) {
    return (x > 20.f) ? x : log1pf(expf(x));
}

// async 16B global -> LDS (wave-uniform base + lane*16; our layout is lane-linear)
__device__ inline void gll16(const void* g, void* l) {
    __builtin_amdgcn_global_load_lds(
        (const __attribute__((address_space(1))) unsigned int*)g,
        (__attribute__((address_space(3))) unsigned int*)l, 16, 0, 0);
}

// ---------------- fused prep: W colsq+transpose (blocks 0..5503), rownorm (rest) ----
__global__ __launch_bounds__(256) void k_prep(const float* __restrict__ vis,
                                              const float* __restrict__ txt,
                                              const float* __restrict__ W,
                                              __hip_bfloat16* __restrict__ Xn,
                                              __hip_bfloat16* __restrict__ WT,
                                              float* __restrict__ colsq) {
    __shared__ __hip_bfloat16 tile[64][65];
    __shared__ float cp[4][64];
    __shared__ float sb[256];
    int t = threadIdx.x;
    if (blockIdx.x < PREP_WBLOCKS) {
        // ---- W prep: 64 classes x 64 features through LDS ----
        int bx = blockIdx.x;
        int c0 = (bx % 172) * 64, f0 = (bx / 172) * 64;
        int tr = t >> 6, tc = t & 63;
        int c = c0 + tc;
        float part = 0.f;
        #pragma unroll
        for (int rr = tr; rr < 64; rr += 4) {
            float w = (c < NCLS) ? W[(size_t)(f0 + rr) * NCLS + c] : 0.f;
            part += w * w;
            tile[rr][tc] = __float2bfloat16(w);
        }
        cp[tr][tc] = part;
        __syncthreads();
        if (tr == 0 && c < NCLS)
            atomicAdd(&colsq[c], cp[0][tc] + cp[1][tc] + cp[2][tc] + cp[3][tc]);
        #pragma unroll
        for (int idx = t; idx < 512; idx += 256) {
            int cc = idx >> 3, ff = (idx & 7) * 8;
            bf16_t tmp[8];
            #pragma unroll
            for (int u = 0; u < 8; ++u) tmp[u] = *(bf16_t*)&tile[ff + u][cc];
            *(uint4*)&WT[(size_t)(c0 + cc) * FEAT + f0 + ff] = *(uint4*)tmp;
        }
    } else {
        // ---- row-normalize [v; t] -> bf16 ----
        int r = blockIdx.x - PREP_WBLOCKS;
        const float* src = (r < BATCH) ? (vis + (size_t)r * FEAT)
                                       : (txt + (size_t)(r - BATCH) * FEAT);
        float4 x0 = ((const float4*)src)[t];
        float4 x1 = ((const float4*)src)[t + 256];
        float ss = x0.x*x0.x + x0.y*x0.y + x0.z*x0.z + x0.w*x0.w
                 + x1.x*x1.x + x1.y*x1.y + x1.z*x1.z + x1.w*x1.w;
        sb[t] = ss; __syncthreads();
        for (int s = 128; s > 0; s >>= 1) { if (t < s) sb[t] += sb[t + s]; __syncthreads(); }
        float rn = rsqrtf(sb[0]);
        __hip_bfloat16* dst = Xn + (size_t)r * FEAT;
        dst[4*t + 0]        = __float2bfloat16(x0.x * rn);
        dst[4*t + 1]        = __float2bfloat16(x0.y * rn);
        dst[4*t + 2]        = __float2bfloat16(x0.z * rn);
        dst[4*t + 3]        = __float2bfloat16(x0.w * rn);
        dst[4*(t+256) + 0]  = __float2bfloat16(x1.x * rn);
        dst[4*(t+256) + 1]  = __float2bfloat16(x1.y * rn);
        dst[4*(t+256) + 2]  = __float2bfloat16(x1.z * rn);
        dst[4*(t+256) + 3]  = __float2bfloat16(x1.w * rn);
    }
}

// ---------------- shared GEMM core: acc[m][n] = sum_k A[m][k]*B[n][k] ----------------
// 128x128 tile, 4 waves 2x2, each wave 64x64 via 4x4 of 16x16x32 MFMA.
// global_load_lds width=16 staging; LDS chunk c (16B) at byte c*16.
__device__ inline void gemm_core(const __hip_bfloat16* __restrict__ A,
                                 const __hip_bfloat16* __restrict__ B,
                                 int m0, int n0,
                                 bf16_t* As, bf16_t* Bs,
                                 floatx4 (&acc)[4][4]) {
    const int t = threadIdx.x;
    const int r0 = t >> 2,         kc0 = t & 3;
    const int r1 = (256 + t) >> 2, kc1 = t & 3;
    const ushort* Ag0 = (const ushort*)(A + (size_t)(m0 + r0) * FEAT + kc0 * 8);
    const ushort* Ag1 = (const ushort*)(A + (size_t)(m0 + r1) * FEAT + kc1 * 8);
    const ushort* Bg0 = (const ushort*)(B + (size_t)(n0 + r0) * FEAT + kc0 * 8);
    const ushort* Bg1 = (const ushort*)(B + (size_t)(n0 + r1) * FEAT + kc1 * 8);
    bf16_t* lA0 = As + t * 8;
    bf16_t* lA1 = As + 2048 + t * 8;
    bf16_t* lB0 = Bs + t * 8;
    bf16_t* lB1 = Bs + 2048 + t * 8;

    const int wave = t >> 6, lane = t & 63;
    const int wm = wave >> 1, wn = wave & 1;
    const int quad = lane >> 4, l16 = lane & 15;
    const bf16x8* Ard[4]; const bf16x8* Brd[4];
    #pragma unroll
    for (int i = 0; i < 4; ++i) {
        Ard[i] = (const bf16x8*)(As + (wm*64 + i*16 + l16) * 32 + quad * 8);
        Brd[i] = (const bf16x8*)(Bs + (wn*64 + i*16 + l16) * 32 + quad * 8);
    }
    for (int kt = 0; kt < FEAT / 32; ++kt) {
        __syncthreads();
        gll16(Ag0, lA0);
        gll16(Ag1, lA1);
        gll16(Bg0, lB0);
        gll16(Bg1, lB1);
        Ag0 += 32; Ag1 += 32; Bg0 += 32; Bg1 += 32;
        __syncthreads();
        bf16x8 af[4], bfr[4];
        #pragma unroll
        for (int i = 0; i < 4; ++i) { af[i] = *Ard[i]; bfr[i] = *Brd[i]; }
        #pragma unroll
        for (int i = 0; i < 4; ++i)
            #pragma unroll
            for (int j = 0; j < 4; ++j)
                acc[i][j] = __builtin_amdgcn_mfma_f32_16x16x32_bf16(af[i], bfr[j], acc[i][j], 0, 0, 0);
    }
}

// ---------------- GEMM1: logits -> LSE partials + label-logit scatter ----------------
// grid (16 m-tiles [x, fastest], 86 n-tiles [y]): consecutive blocks share the WT n-tile.
__global__ __launch_bounds__(256) void k_gemm_lse(const __hip_bfloat16* __restrict__ Xn,
                                                  const __hip_bfloat16* __restrict__ WT,
                                                  const float* __restrict__ colsq,
                                                  const int* __restrict__ labels,
                                                  float* __restrict__ pmax,
                                                  float* __restrict__ psum,
                                                  float* __restrict__ ll) {
    __shared__ bf16_t As[128 * 32], Bs[128 * 32];
    floatx4 acc[4][4] = {};
    int m0 = blockIdx.x * 128, n0 = blockIdx.y * 128;
    gemm_core(Xn, WT, m0, n0, As, Bs, acc);

    const int t = threadIdx.x, wave = t >> 6, lane = t & 63;
    const int wm = wave >> 1, wn = wave & 1, quad = lane >> 4, l16 = lane & 15;
    float rcol[4]; bool val[4];
    #pragma unroll
    for (int j = 0; j < 4; ++j) {
        int nj = n0 + wn*64 + j*16 + l16;
        val[j] = (nj < NCLS);
        rcol[j] = val[j] ? rsqrtf(colsq[nj]) : 0.f;
    }
    const int pidx = blockIdx.y * 2 + wn;
    #pragma unroll
    for (int i = 0; i < 4; ++i) {
        #pragma unroll
        for (int reg = 0; reg < 4; ++reg) {
            int m = m0 + wm*64 + i*16 + quad*4 + reg;
            int lm = labels[m & (BATCH - 1)];
            float v[4]; float mx = -1e30f;
            #pragma unroll
            for (int j = 0; j < 4; ++j) {
                v[j] = val[j] ? (C_SCALE * acc[i][j][reg] * rcol[j]) : -1e30f;
                mx = fmaxf(mx, v[j]);
            }
            // label-logit scatter: each row's label class lives in exactly one column slice
            #pragma unroll
            for (int j = 0; j < 4; ++j) {
                int nj = n0 + wn*64 + j*16 + l16;
                if (nj == lm) ll[m] = v[j];
            }
            for (int off = 1; off < 16; off <<= 1) mx = fmaxf(mx, __shfl_xor(mx, off));
            float s = 0.f;
            #pragma unroll
            for (int j = 0; j < 4; ++j) if (val[j]) s += expf(v[j] - mx);
            for (int off = 1; off < 16; off <<= 1) s += __shfl_xor(s, off);
            if (l16 == 0) {
                pmax[(size_t)m * NPART + pidx] = mx;
                psum[(size_t)m * NPART + pidx] = s;
            }
        }
    }
}

// ---------------- GEMM2: sim = v . t^T -> masked softplus sum (64x64 tiles) ---------
__global__ __launch_bounds__(256) void k_gemm_sim(const __hip_bfloat16* __restrict__ Xn,
                                                  const int* __restrict__ labels,
                                                  float* __restrict__ align_sum) {
    __shared__ bf16_t As[64 * 32], Bs[64 * 32];
    const __hip_bfloat16* A = Xn;
    const __hip_bfloat16* B = Xn + (size_t)BATCH * FEAT;
    floatx4 acc[2][2] = {};
    int m0 = blockIdx.x * 64, n0 = blockIdx.y * 64;
    const int t = threadIdx.x;
    const int r0 = t >> 2, kc0 = t & 3;
    const ushort* Ag = (const ushort*)(A + (size_t)(m0 + r0) * FEAT + kc0 * 8);
    const ushort* Bg = (const ushort*)(B + (size_t)(n0 + r0) * FEAT + kc0 * 8);
    bf16_t* lA = As + t * 8;
    bf16_t* lB = Bs + t * 8;
    const int wave = t >> 6, lane = t & 63;
    const int wm = wave >> 1, wn = wave & 1, quad = lane >> 4, l16 = lane & 15;
    const bf16x8* Ard[2]; const bf16x8* Brd[2];
    #pragma unroll
    for (int i = 0; i < 2; ++i) {
        Ard[i] = (const bf16x8*)(As + (wm*32 + i*16 + l16) * 32 + quad * 8);
        Brd[i] = (const bf16x8*)(Bs + (wn*32 + i*16 + l16) * 32 + quad * 8);
    }
    for (int kt = 0; kt < FEAT / 32; ++kt) {
        __syncthreads();
        gll16(Ag, lA);
        gll16(Bg, lB);
        Ag += 32; Bg += 32;
        __syncthreads();
        bf16x8 af[2], bfr[2];
        #pragma unroll
        for (int i = 0; i < 2; ++i) { af[i] = *Ard[i]; bfr[i] = *Brd[i]; }
        #pragma unroll
        for (int i = 0; i < 2; ++i)
            #pragma unroll
            for (int j = 0; j < 2; ++j)
                acc[i][j] = __builtin_amdgcn_mfma_f32_16x16x32_bf16(af[i], bfr[j], acc[i][j], 0, 0, 0);
    }
    int ln[2];
    #pragma unroll
    for (int j = 0; j < 2; ++j) ln[j] = labels[n0 + wn*32 + j*16 + l16];
    float tot = 0.f;
    #pragma unroll
    for (int i = 0; i < 2; ++i) {
        #pragma unroll
        for (int reg = 0; reg < 4; ++reg) {
            int m = m0 + wm*32 + i*16 + quad*4 + reg;
            int lm = labels[m];
            #pragma unroll
            for (int j = 0; j < 2; ++j) {
                float s = acc[i][j][reg];
                float arg = (lm == ln[j]) ? (-C_SPOS * (s - C_ALPHA))
                                          : ( C_SNEG * (s - C_BETA));
                tot += softplusf(arg);
            }
        }
    }
    for (int off = 1; off < 64; off <<= 1) tot += __shfl_xor(tot, off);
    if (lane == 0) atomicAdd(align_sum, tot);
}

// ---------------- merge partials -> CE sum (atomic) ----------------
__global__ __launch_bounds__(256) void k_merge(const float* __restrict__ pmax,
                                               const float* __restrict__ psum,
                                               const float* __restrict__ ll,
                                               float* __restrict__ inst_sum) {
    int r = blockIdx.x, t = threadIdx.x;
    float mx = -1e30f, sm = 0.f;
    if (t < NPART) { mx = pmax[(size_t)r * NPART + t]; sm = psum[(size_t)r * NPART + t]; }
    __shared__ float sb[256];
    sb[t] = mx; __syncthreads();
    for (int s = 128; s > 0; s >>= 1) { if (t < s) sb[t] = fmaxf(sb[t], sb[t+s]); __syncthreads(); }
    float M = sb[0]; __syncthreads();
    float c = sm * expf(mx - M);
    sb[t] = c; __syncthreads();
    for (int s = 128; s > 0; s >>= 1) { if (t < s) sb[t] += sb[t+s]; __syncthreads(); }
    if (t == 0) atomicAdd(inst_sum, M + logf(sb[0]) - ll[r]);
}

// ---------------- final: two scalars ----------------
__global__ __launch_bounds__(64) void k_final(const float* __restrict__ inst_sum,
                                              const float* __restrict__ align_sum,
                                              float* __restrict__ out) {
    if (threadIdx.x == 0) {
        out[0] = inst_sum[0] / (float)BATCH;
        out[1] = align_sum[0] * 2.f / (float)BATCH;
    }
}

extern "C" void kernel_launch(void* const* d_in, const int* in_sizes, int n_in,
                              void* d_out, int out_size, void* d_ws, size_t ws_size,
                              hipStream_t stream) {
    const float* vis    = (const float*)d_in[0];
    const float* txt    = (const float*)d_in[1];
    const int*   labels = (const int*)  d_in[2];
    const float* W      = (const float*)d_in[3];
    float* out = (float*)d_out;
    char*  ws  = (char*)d_ws;

    float* align_sum = (float*)(ws + O_ALIGN);
    float* inst_sum  = (float*)(ws + O_INST);
    float* colsq     = (float*)(ws + O_COLSQ);
    __hip_bfloat16* Xn = (__hip_bfloat16*)(ws + O_XN);
    __hip_bfloat16* WT = (__hip_bfloat16*)(ws + O_WT);
    float* pmax = (float*)(ws + O_PMAX);
    float* psum = (float*)(ws + O_PSUM);
    float* ll   = (float*)(ws + O_LL);

    hipMemsetAsync(ws, 0, O_XN, stream);  // zero align/inst/colsq

    k_prep    <<<dim3(PREP_TOTAL), 256, 0, stream>>>(vis, txt, W, Xn, WT, colsq);
    k_gemm_lse<<<dim3(M1 / 128, NT1), 256, 0, stream>>>(Xn, WT, colsq, labels, pmax, psum, ll);
    k_gemm_sim<<<dim3(BATCH / 64, BATCH / 64), 256, 0, stream>>>(Xn, labels, align_sum);
    k_merge   <<<dim3(M1), 256, 0, stream>>>(pmax, psum, ll, inst_sum);
    k_final   <<<dim3(1), 64, 0, stream>>>(inst_sum, align_sum, out);
}